// Round 9
// baseline (395.050 us; speedup 1.0000x reference)
//
#include <hip/hip_runtime.h>
#include <cstdint>

typedef unsigned int u32;
typedef unsigned long long u64;
typedef unsigned short u16;

#define BATCH 4
#define A_CNT 70400
#define FEAT 27648
#define KSPLIT 16
#define KCHUNK 1728          // FEAT/KSPLIT
#define NTILE_IT 27          // KCHUNK/64

typedef __attribute__((ext_vector_type(8))) short bf16x8;
typedef __attribute__((ext_vector_type(4))) float f32x4;
typedef __attribute__((ext_vector_type(4))) u32 u32x4;

// ---------------- workspace layout ----------------
constexpr size_t OF_KEYS = 0;                         // 4*70400*4 = 1126400
constexpr size_t OF_TBOX = OF_KEYS + 1126400;         // 114688
constexpr size_t OF_TSC  = OF_TBOX + 114688;          // 16384
constexpr size_t OF_BX1  = OF_TSC + 16384;
constexpr size_t OF_BX2  = OF_BX1 + 16384;
constexpr size_t OF_BY1  = OF_BX2 + 16384;
constexpr size_t OF_BY2  = OF_BY1 + 16384;
constexpr size_t OF_BAR  = OF_BY2 + 16384;
constexpr size_t OF_MASK = OF_BAR + 16384;            // 524288
constexpr size_t OF_ROIS = OF_MASK + 524288;          // 57344
constexpr size_t OF_RSC  = OF_ROIS + 57344;           // 8192
constexpr size_t OF_BSW  = OF_RSC + 8192;             // 14155776
constexpr size_t OF_PART = OF_BSW + 14155776;         // 33554432
constexpr size_t WS_NEED = OF_PART + 33554432;

// ---------------- helpers ----------------
__device__ __forceinline__ u32 keyOf(float f) {
  u32 u = __float_as_uint(f);
  return (u & 0x80000000u) ? ~u : (u | 0x80000000u);
}
__device__ __forceinline__ float keyToF(u32 k) {
  u32 u = (k & 0x80000000u) ? (k ^ 0x80000000u) : ~k;
  return __uint_as_float(u);
}
__device__ __forceinline__ u16 f2bf(float f) {   // RNE f32 -> bf16
  u32 u = __float_as_uint(f);
  u32 r = 0x7FFFu + ((u >> 16) & 1u);
  return (u16)((u + r) >> 16);
}
__device__ __forceinline__ void gload_lds16(const void* g, void* l) {
  auto gp = reinterpret_cast<const __attribute__((address_space(1))) unsigned int*>(
      reinterpret_cast<uintptr_t>(g));
  auto lp = reinterpret_cast<__attribute__((address_space(3))) unsigned int*>(
      reinterpret_cast<uintptr_t>(l));
  __builtin_amdgcn_global_load_lds(gp, lp, 16, 0, 0);
}
__device__ __forceinline__ u64 shflx64(u64 v, int m) {
  u32 lo = (u32)v, hi = (u32)(v >> 32);
  lo = __shfl_xor(lo, m, 64);
  hi = __shfl_xor(hi, m, 64);
  return ((u64)hi << 32) | lo;
}
// wave-aggregated histogram add: one atomic per UNIQUE bin per wave-instruction
__device__ __forceinline__ void waveHistAdd(u32* h, u32 bin, bool valid, int lane) {
  u64 active = __ballot(valid);
  while (active) {
    int leader = __ffsll(active) - 1;
    u32 lbin = __shfl(bin, leader, 64);
    u64 match = __ballot(valid && (bin == lbin)) & active;
    if (lane == leader) atomicAdd(&h[lbin], (u32)__popcll(match));
    active &= ~match;
  }
}

// ---------------- fatA: blocks 0-3 proposal pipeline; blocks 4-867 Bsw prep ----------------
__global__ __launch_bounds__(1024) void k_fatA(const float* __restrict__ cls,
    const float* __restrict__ boxes, const float* __restrict__ Ws1,
    u32* __restrict__ keys, float* __restrict__ tbox, float* __restrict__ tsc,
    float* __restrict__ bx1, float* __restrict__ bx2, float* __restrict__ by1,
    float* __restrict__ by2, float* __restrict__ bar, u32* __restrict__ Bsw)
{
  int bid = blockIdx.x;
  int t = threadIdx.x;
  if (bid >= 4) {
    // ---- Bsw prep: Ws1 -> swizzled bf16 tiles ----
    u32 w = (u32)(bid - 4) * 1024u + t;  // u32x4 index (884736 total)
    u32 tile = w >> 11;                  // 2048 u32x4 per 32KB tile
    u32 rem = w & 2047u;
    u32 n = rem >> 3;                    // row 0..255
    u32 pq = (rem & 7u) << 4;            // 16B-aligned byte pos in row
    u32 q0 = pq ^ ((n & 7u) << 4);       // inverse-swizzled logical byte
    u32 col0 = tile * 64u + (q0 >> 1);
    const float* src = Ws1 + (size_t)n * FEAT + col0;
    float4 f0 = *(const float4*)src;
    float4 f1 = *(const float4*)(src + 4);
    u32x4 o;
    o.x = (u32)f2bf(f0.x) | ((u32)f2bf(f0.y) << 16);
    o.y = (u32)f2bf(f0.z) | ((u32)f2bf(f0.w) << 16);
    o.z = (u32)f2bf(f1.x) | ((u32)f2bf(f1.y) << 16);
    o.w = (u32)f2bf(f1.z) | ((u32)f2bf(f1.w) << 16);
    ((u32x4*)Bsw)[w] = o;
    return;
  }
  // ---- proposal: ballot-aggregated two-level threshold + compact + sort ----
  int b = bid;
  int lane = t & 63;
  __shared__ u64 s[2048];
  __shared__ u32 h8[256];
  __shared__ u32 buf[256];
  __shared__ u32 sh_above, cc;
  __shared__ int selb, selk;
  const float* cb = cls + (size_t)b * A_CNT * 3;
  u32* kb = keys + (size_t)b * A_CNT;

  for (int i = t; i < 256; i += 1024) h8[i] = 0u;
  if (t == 0) cc = 0u;
  __syncthreads();

  // phase A: keys + hi-8 histogram (2-stage load prefetch, aggregated atomics)
  {
    float s0n = cb[(size_t)t * 3 + 0];
    float s1n = cb[(size_t)t * 3 + 1];
    float s2n = cb[(size_t)t * 3 + 2];
#pragma unroll 1
    for (int i = 0; i < 69; ++i) {
      float s0 = s0n, s1 = s1n, s2 = s2n;
      int gn = t + ((i + 1) << 10);
      if (i < 68 && gn < A_CNT) {
        s0n = cb[(size_t)gn * 3 + 0];
        s1n = cb[(size_t)gn * 3 + 1];
        s2n = cb[(size_t)gn * 3 + 2];
      }
      int g = t + (i << 10);
      bool valid = (g < A_CNT);
      u32 k = 0u;
      if (valid) {
        k = keyOf(fmaxf(s0, fmaxf(s1, s2)));
        kb[g] = k;
      }
      waveHistAdd(h8, k >> 24, valid, lane);
    }
  }
  __syncthreads();
  if (t < 256) buf[t] = h8[t];
  __syncthreads();
  for (int d = 1; d < 256; d <<= 1) {
    u32 v = (t < 256 && t + d < 256) ? buf[t + d] : 0u;
    __syncthreads();
    if (t < 256) buf[t] += v;
    __syncthreads();
  }
  if (t < 256 && buf[t] >= 1024u && (t == 255 || buf[t + 1] < 1024u)) selb = t;
  __syncthreads();
  int b8 = selb;
  if (t == 0) sh_above = (b8 == 255) ? 0u : buf[b8 + 1];
  __syncthreads();
  for (int i = t; i < 256; i += 1024) h8[i] = 0u;
  __syncthreads();
  // phase B: lo-8 histogram within selected hi-8 bin (few active lanes)
#pragma unroll 2
  for (int i = 0; i < 69; ++i) {
    int g = t + (i << 10);
    u32 k = (g < A_CNT) ? kb[g] : 0u;
    bool act = (g < A_CNT) && ((int)(k >> 24) == b8);
    waveHistAdd(h8, (k >> 16) & 255u, act, lane);
  }
  __syncthreads();
  if (t < 256) buf[t] = h8[t];
  __syncthreads();
  for (int d = 1; d < 256; d <<= 1) {
    u32 v = (t < 256 && t + d < 256) ? buf[t + d] : 0u;
    __syncthreads();
    if (t < 256) buf[t] += v;
    __syncthreads();
  }
  u32 above = sh_above;
  if (t < 256 && above + buf[t] >= 1024u &&
      (t == 255 || above + buf[t + 1] < 1024u)) selk = t;
  __syncthreads();
  u32 kth = ((u32)b8 << 8) | (u32)selk;
  // phase C: aggregated compaction into LDS
#pragma unroll 2
  for (int i = 0; i < 69; ++i) {
    int g = t + (i << 10);
    u32 k = (g < A_CNT) ? kb[g] : 0u;
    bool pass = (g < A_CNT) && ((k >> 16) >= kth);
    u64 mm = __ballot(pass);
    if (mm) {
      int leader = __ffsll(mm) - 1;
      u32 base = 0;
      if (lane == leader) base = atomicAdd(&cc, (u32)__popcll(mm));
      base = __shfl(base, leader, 64);
      if (pass) {
        u32 pos = base + (u32)__popcll(mm & ((1ull << lane) - 1ull));
        if (pos < 2048u) s[pos] = ((u64)k << 32) | (u32)(~(u32)g);
      }
    }
  }
  __syncthreads();
  u32 m = cc; if (m > 2048u) m = 2048u;
  for (int e = t; e < 2048; e += 1024) if (e >= (int)m) s[e] = 0ull;
  __syncthreads();
  // ---- hybrid bitonic sort 2048 desc: reg levels (shfl) + LDS passes ----
  {
    u64 v0 = s[2 * t], v1 = s[2 * t + 1];
#pragma unroll
    for (u32 k = 2; k <= 128; k <<= 1) {
      bool desc = ((t & (k >> 1)) == 0);
#pragma unroll
      for (u32 j = (k >> 1); j >= 2; j >>= 1) {
        u32 mmk = j >> 1;
        u64 p0 = shflx64(v0, mmk);
        u64 p1 = shflx64(v1, mmk);
        bool up = ((t & mmk) == 0);
        bool mx = (desc == up);
        v0 = mx ? (v0 > p0 ? v0 : p0) : (v0 < p0 ? v0 : p0);
        v1 = mx ? (v1 > p1 ? v1 : p1) : (v1 < p1 ? v1 : p1);
      }
      if (desc ? (v0 < v1) : (v0 > v1)) { u64 tmp = v0; v0 = v1; v1 = tmp; }
    }
    s[2 * t] = v0; s[2 * t + 1] = v1;
    __syncthreads();
    for (u32 k = 256; k <= 2048; k <<= 1) {
      for (u32 j = k >> 1; j >= 128; j >>= 1) {
        for (int e = t; e < 2048; e += 1024) {
          u32 p = (u32)e ^ j;
          if (p > (u32)e) {
            bool d2 = ((e & k) == 0);
            u64 x = s[e], y = s[p];
            if (d2 ? (x < y) : (x > y)) { s[e] = y; s[p] = x; }
          }
        }
        __syncthreads();
      }
      v0 = s[2 * t]; v1 = s[2 * t + 1];
      bool desc = ((t & (k >> 1)) == 0);
#pragma unroll
      for (u32 j = 64; j >= 2; j >>= 1) {
        u32 mmk = j >> 1;
        u64 p0 = shflx64(v0, mmk);
        u64 p1 = shflx64(v1, mmk);
        bool up = ((t & mmk) == 0);
        bool mx = (desc == up);
        v0 = mx ? (v0 > p0 ? v0 : p0) : (v0 < p0 ? v0 : p0);
        v1 = mx ? (v1 > p1 ? v1 : p1) : (v1 < p1 ? v1 : p1);
      }
      if (desc ? (v0 < v1) : (v0 > v1)) { u64 tmp = v0; v0 = v1; v1 = tmp; }
      s[2 * t] = v0; s[2 * t + 1] = v1;
      __syncthreads();
    }
  }
  // ---- geometry tail ----
  u64 comp = s[t];
  u32 kk = (u32)(comp >> 32);
  u32 a = ~(u32)(comp & 0xFFFFFFFFull);
  int o = b * 1024 + t;
  tsc[o] = keyToF(kk);
  const float* bp = boxes + ((size_t)b * A_CNT + a) * 7;
  float x = bp[0], y = bp[1], z = bp[2], dx = bp[3], dy = bp[4], dz = bp[5], rr = bp[6];
  float* tb = tbox + (size_t)o * 7;
  tb[0] = x; tb[1] = y; tb[2] = z; tb[3] = dx; tb[4] = dy; tb[5] = dz; tb[6] = rr;
  {
#pragma clang fp contract(off)
    bx1[o] = x - 0.5f * dx; bx2[o] = x + 0.5f * dx;
    by1[o] = y - 0.5f * dy; by2[o] = y + 0.5f * dy;
    bar[o] = dx * dy;
  }
}

// ---------------- fatB: blocks 0-511 GEMM1 (XCD-swizzled split-K); 512-767 IoU masks ----------------
__global__ __launch_bounds__(256) void k_fatB(const float* __restrict__ A,
    const u32* __restrict__ Bsw, float* __restrict__ part,
    const float* __restrict__ bx1, const float* __restrict__ bx2,
    const float* __restrict__ by1, const float* __restrict__ by2,
    const float* __restrict__ bar, u32* __restrict__ mask)
{
  __shared__ u32x4 Alds4[64 * 8];    // 8 KB
  __shared__ u32x4 Blds4[256 * 8];   // 32 KB
  int bid = blockIdx.x;
  if (bid >= 512) {
    int mi = bid - 512;
    int b = mi >> 6;
    int cbk = (mi >> 2) & 15;
    int rb0 = (mi & 3) * 4;
    int tt = threadIdx.x;
    int rbi = tt >> 6, ln = tt & 63;
    int r = (rb0 + rbi) * 64 + ln;
    int o = b * 1024, jc0 = cbk * 64;
    __shared__ float cx1[64], cx2[64], cy1[64], cy2[64], car[64];
    if (tt < 64) {
      cx1[tt] = bx1[o + jc0 + tt]; cx2[tt] = bx2[o + jc0 + tt];
      cy1[tt] = by1[o + jc0 + tt]; cy2[tt] = by2[o + jc0 + tt];
      car[tt] = bar[o + jc0 + tt];
    }
    __syncthreads();
    float rx1 = bx1[o + r], rx2 = bx2[o + r], ry1 = by1[o + r], ry2 = by2[o + r], rar = bar[o + r];
    u32 w0 = 0, w1 = 0;
    {
#pragma clang fp contract(off)
      for (int c = 0; c < 64; ++c) {
        int jc = jc0 + c;
        float iw = fminf(rx2, cx2[c]) - fmaxf(rx1, cx1[c]); iw = fmaxf(iw, 0.0f);
        float ih = fminf(ry2, cy2[c]) - fmaxf(ry1, cy1[c]); ih = fmaxf(ih, 0.0f);
        float inter = iw * ih;
        float den = fmaxf(rar + car[c] - inter, 1e-6f);
        float iou = inter / den;
        if ((iou > 0.7f) && (jc > r)) {
          if (c < 32) w0 |= 1u << c; else w1 |= 1u << (c - 32);
        }
      }
    }
    mask[((size_t)(o + r)) * 32 + cbk * 2 + 0] = w0;
    mask[((size_t)(o + r)) * 32 + cbk * 2 + 1] = w1;
    return;
  }
  // ---- GEMM path ----
  char* Alds = (char*)Alds4;
  char* Blds = (char*)Blds4;
  int q = bid >> 3;                    // 0..63
  int ks = (bid & 7) * 2 + (q >> 5);   // XCD-local K-chunk
  int mt = q & 31;
  int tid = threadIdx.x, lane = tid & 63, wv = tid >> 6;

  f32x4 acc[4][4];
#pragma unroll
  for (int i = 0; i < 4; ++i)
#pragma unroll
    for (int j = 0; j < 4; ++j) acc[i][j] = (f32x4){0.f, 0.f, 0.f, 0.f};

  int am = tid >> 2;
  int ak = (tid & 3) * 16;
  const float* ap_base = A + ((size_t)(mt * 64 + am)) * FEAT + (size_t)ks * KCHUNK + ak;
  int asw = (am & 7) << 4;
  int ac0 = (tid & 3) * 32;
  char* aw0 = Alds + am * 128 + ((ac0) ^ asw);
  char* aw1 = Alds + am * 128 + ((ac0 + 16) ^ asw);
  const char* bsrc_base = (const char*)Bsw + ((size_t)(ks * NTILE_IT)) * 32768 + (wv * 8) * 1024 + lane * 16;
  char* bdst_base = Blds + (wv * 8) * 1024;

  int row16 = lane & 15, kgrp = lane >> 4;
  int aoff[4][2], boff[4][2];
#pragma unroll
  for (int ksub = 0; ksub < 2; ++ksub) {
    int qq = ksub * 64 + kgrp * 16;
#pragma unroll
    for (int mf = 0; mf < 4; ++mf) {
      int row = mf * 16 + row16;
      aoff[mf][ksub] = row * 128 + (qq ^ ((row & 7) << 4));
    }
#pragma unroll
    for (int nf = 0; nf < 4; ++nf) {
      int n = wv * 64 + nf * 16 + row16;
      boff[nf][ksub] = n * 128 + (qq ^ ((n & 7) << 4));
    }
  }

  for (int it = 0; it < NTILE_IT; ++it) {
    const float4* ap = (const float4*)(ap_base + it * 64);
    float4 f0 = ap[0], f1 = ap[1], f2 = ap[2], f3 = ap[3];
    u32x4 c0, c1;
    c0.x = (u32)f2bf(f0.x) | ((u32)f2bf(f0.y) << 16);
    c0.y = (u32)f2bf(f0.z) | ((u32)f2bf(f0.w) << 16);
    c0.z = (u32)f2bf(f1.x) | ((u32)f2bf(f1.y) << 16);
    c0.w = (u32)f2bf(f1.z) | ((u32)f2bf(f1.w) << 16);
    c1.x = (u32)f2bf(f2.x) | ((u32)f2bf(f2.y) << 16);
    c1.y = (u32)f2bf(f2.z) | ((u32)f2bf(f2.w) << 16);
    c1.z = (u32)f2bf(f3.x) | ((u32)f2bf(f3.y) << 16);
    c1.w = (u32)f2bf(f3.z) | ((u32)f2bf(f3.w) << 16);
    *(u32x4*)aw0 = c0;
    *(u32x4*)aw1 = c1;
    const char* bs = bsrc_base + (size_t)it * 32768;
#pragma unroll
    for (int i = 0; i < 8; ++i) gload_lds16(bs + i * 1024, bdst_base + i * 1024);
    __syncthreads();
    bf16x8 af[4][2], bfv[4][2];
#pragma unroll
    for (int ksub = 0; ksub < 2; ++ksub) {
#pragma unroll
      for (int mf = 0; mf < 4; ++mf) af[mf][ksub] = *(const bf16x8*)(Alds + aoff[mf][ksub]);
#pragma unroll
      for (int nf = 0; nf < 4; ++nf) bfv[nf][ksub] = *(const bf16x8*)(Blds + boff[nf][ksub]);
    }
#pragma unroll
    for (int ksub = 0; ksub < 2; ++ksub)
#pragma unroll
      for (int mf = 0; mf < 4; ++mf)
#pragma unroll
        for (int nf = 0; nf < 4; ++nf)
          acc[mf][nf] = __builtin_amdgcn_mfma_f32_16x16x32_bf16(af[mf][ksub], bfv[nf][ksub], acc[mf][nf], 0, 0, 0);
    __syncthreads();
  }
  float* pb = part + (size_t)ks * 524288;
#pragma unroll
  for (int mf = 0; mf < 4; ++mf) {
    int row = mt * 64 + mf * 16 + kgrp * 4;
#pragma unroll
    for (int nf = 0; nf < 4; ++nf) {
      int col = wv * 64 + nf * 16 + row16;
#pragma unroll
      for (int rr = 0; rr < 4; ++rr)
        pb[(size_t)(row + rr) * 256 + col] = acc[mf][nf][rr];
    }
  }
}

// ---------------- chunked sequential greedy NMS + compact to rois ----------------
__global__ __launch_bounds__(64) void k_nms(const u32* __restrict__ mask,
    const float* __restrict__ tbox, const float* __restrict__ tsc,
    float* __restrict__ rois, float* __restrict__ rsc)
{
  int b = blockIdx.x;
  int lane = threadIdx.x;
  int el = lane & 31;
  const u32* M = mask + (size_t)b * 1024 * 32;
  u32 R = 0;
  u32 cur[32], nxt[32];
#pragma unroll
  for (int i = 0; i < 32; ++i) cur[i] = M[(size_t)(i * 32 + el)];
#pragma unroll 1
  for (int c = 0; c < 32; ++c) {
    if (c < 31) {
      int nb = (c + 1) * 1024 + el;
#pragma unroll
      for (int i = 0; i < 32; ++i) nxt[i] = M[(size_t)(nb + i * 32)];
    }
    u32 w = R;
#pragma unroll
    for (int i = 0; i < 32; ++i) w |= ((w >> i) & 1u) ? 0u : cur[i];
    u32 wfin = __shfl(w, c, 64);
#pragma unroll
    for (int i = 0; i < 32; ++i) R |= ((wfin >> i) & 1u) ? 0u : cur[i];
#pragma unroll
    for (int i = 0; i < 32; ++i) cur[i] = nxt[i];
  }
  u32 keepw = (lane < 32) ? ~R : 0u;
  int c = __popc(keepw);
  int pre = c;
  for (int d = 1; d < 64; d <<= 1) {
    int v = __shfl_up(pre, d, 64);
    if (lane >= d) pre += v;
  }
  int total = __shfl(pre, 31, 64);
  int base = pre - c;
  if (lane < 32) {
    u32 w = keepw;
    int rank = base;
    while (w) {
      int bit = __ffs(w) - 1;
      w &= w - 1;
      if (rank < 512) {
        int r = lane * 32 + bit;
        const float* tb = tbox + ((size_t)b * 1024 + r) * 7;
        float* rp = rois + ((size_t)b * 512 + rank) * 7;
        rp[0] = tb[0]; rp[1] = tb[1]; rp[2] = tb[2]; rp[3] = tb[3];
        rp[4] = tb[4]; rp[5] = tb[5]; rp[6] = tb[6];
        rsc[b * 512 + rank] = tsc[b * 1024 + r];
      }
      rank++;
    }
  }
  for (int z = total + lane; z < 512; z += 64) {
    float* rp = rois + ((size_t)b * 512 + z) * 7;
    rp[0] = rp[1] = rp[2] = rp[3] = rp[4] = rp[5] = rp[6] = 0.0f;
    rsc[b * 512 + z] = 0.0f;
  }
}

// ---------------- one 256x256 layer (4 rows per thread-half) + BN + ReLU ----------------
__device__ __forceinline__ void layer4(const float (*IN)[256], const float* __restrict__ W,
    const float* __restrict__ g, const float* __restrict__ bb, float (*OUT)[256], int t, int h)
{
  float acc[4] = {0, 0, 0, 0};
  const float* Wrow = W + (size_t)t * 256;
  for (int k = 0; k < 256; k += 4) {
    float4 w4 = *(const float4*)&Wrow[k];
#pragma unroll
    for (int r = 0; r < 4; ++r) {
      float4 xv = *(const float4*)&IN[h * 4 + r][k];
      acc[r] = fmaf(xv.x, w4.x, acc[r]);
      acc[r] = fmaf(xv.y, w4.y, acc[r]);
      acc[r] = fmaf(xv.z, w4.z, acc[r]);
      acc[r] = fmaf(xv.w, w4.w, acc[r]);
    }
  }
  float sc = g[t] / sqrtf(1.0f + 1e-5f);
  float bv = bb[t];
#pragma unroll
  for (int r = 0; r < 4; ++r)
    OUT[h * 4 + r][t] = fmaxf(fmaf(acc[r], sc, bv), 0.0f);
}

// ---------------- fused head chain (512 threads) ----------------
__global__ __launch_bounds__(512) void k_chain(const float* __restrict__ part,
    const float* __restrict__ Ws2, const float* __restrict__ Wc1, const float* __restrict__ Wc2,
    const float* __restrict__ Wr1, const float* __restrict__ Wr2,
    const float* __restrict__ g1, const float* __restrict__ b1,
    const float* __restrict__ g2, const float* __restrict__ b2,
    const float* __restrict__ gc1, const float* __restrict__ bc1,
    const float* __restrict__ gc2, const float* __restrict__ bc2,
    const float* __restrict__ gr1, const float* __restrict__ br1,
    const float* __restrict__ gr2, const float* __restrict__ br2,
    const float* __restrict__ Wc3, const float* __restrict__ bc3,
    const float* __restrict__ Wr3, const float* __restrict__ br3,
    const float* __restrict__ rois, const float* __restrict__ rsc,
    float* __restrict__ out)
{
  int bid = blockIdx.x, tid = threadIdx.x;
  int t = tid & 255, h = tid >> 8;        // h: row-half (rows h*4..h*4+3)
  __shared__ __align__(16) float bufX[8][256];
  __shared__ __align__(16) float bufY[8][256];
  __shared__ __align__(16) float bufC[8][256];
  __shared__ __align__(16) float bufR[8][256];
  __shared__ float hd[64];
  {
    float sc = g1[t] / sqrtf(1.0f + 1e-5f);
    float bv = b1[t];
#pragma unroll
    for (int r = 0; r < 4; ++r) {
      int row = h * 4 + r;
      float s = 0.f;
#pragma unroll
      for (int ks = 0; ks < KSPLIT; ++ks)
        s += part[(size_t)ks * 524288 + (size_t)(bid * 8 + row) * 256 + t];
      bufX[row][t] = fmaxf(fmaf(s, sc, bv), 0.0f);
    }
  }
  __syncthreads();
  layer4(bufX, Ws2, g2, b2, bufY, t, h);          // x2
  __syncthreads();
  layer4(bufY, Wc1, gc1, bc1, bufC, t, h);        // c1
  layer4(bufY, Wr1, gr1, br1, bufR, t, h);        // r1
  __syncthreads();
  layer4(bufC, Wc2, gc2, bc2, bufX, t, h);        // c2 -> bufX
  layer4(bufR, Wr2, gr2, br2, bufY, t, h);        // r2 -> bufY
  __syncthreads();
  int wv = tid >> 6, ln = tid & 63;
  for (int task = wv; task < 64; task += 8) {
    float p;
    if (task < 8) {
      float4 yv = *(const float4*)&bufX[task][ln * 4];
      float4 w4 = ((const float4*)Wc3)[ln];
      p = yv.x * w4.x + yv.y * w4.y + yv.z * w4.z + yv.w * w4.w;
    } else {
      int i = task - 8, row = i / 7, j = i % 7;
      float4 yv = *(const float4*)&bufY[row][ln * 4];
      float4 w4 = ((const float4*)(Wr3 + j * 256))[ln];
      p = yv.x * w4.x + yv.y * w4.y + yv.z * w4.z + yv.w * w4.w;
    }
#pragma unroll
    for (int off = 32; off > 0; off >>= 1) p += __shfl_xor(p, off, 64);
    if (ln == 0) hd[task] = p;
  }
  __syncthreads();
  if (tid < 8) {
    int m = bid * 8 + tid;
    float clsv = hd[tid] + bc3[0];
    float rg[7];
#pragma unroll
    for (int j = 0; j < 7; ++j) rg[j] = hd[8 + tid * 7 + j] + br3[j];
    const float* R = rois + (size_t)m * 7;
    float rx = R[0], ry = R[1], rz = R[2], dxa = R[3], dya = R[4], dza = R[5], ra = R[6];
    float diag = sqrtf(dxa * dxa + dya * dya);
    float x = rg[0] * diag, y = rg[1] * diag, z = rg[2] * dza;
    float ex = expf(rg[3]) * dxa, ey = expf(rg[4]) * dya, ez = expf(rg[5]) * dza;
    float hr = rg[6] + ra;
    float cc = cosf(ra), sn = sinf(ra);
    float xr = x * cc - y * sn, yr = x * sn + y * cc;
    float* O = out + (size_t)m * 9;
    O[0] = clsv; O[1] = xr + rx; O[2] = yr + ry; O[3] = z + rz;
    O[4] = ex; O[5] = ey; O[6] = ez; O[7] = hr; O[8] = rsc[m];
  }
}

// ---------------- launch ----------------
extern "C" void kernel_launch(void* const* d_in, const int* in_sizes, int n_in,
                              void* d_out, int out_size, void* d_ws, size_t ws_size,
                              hipStream_t stream)
{
  const float* rpn_box = (const float*)d_in[0];
  const float* rpn_cls = (const float*)d_in[1];
  const float* pooled  = (const float*)d_in[2];
  const float* Ws1 = (const float*)d_in[3];
  const float* g1  = (const float*)d_in[4];
  const float* b1  = (const float*)d_in[5];
  const float* Ws2 = (const float*)d_in[6];
  const float* g2  = (const float*)d_in[7];
  const float* b2  = (const float*)d_in[8];
  const float* Wc1 = (const float*)d_in[9];
  const float* gc1 = (const float*)d_in[10];
  const float* bc1 = (const float*)d_in[11];
  const float* Wc2 = (const float*)d_in[12];
  const float* gc2 = (const float*)d_in[13];
  const float* bc2 = (const float*)d_in[14];
  const float* Wc3 = (const float*)d_in[15];
  const float* bc3 = (const float*)d_in[16];
  const float* Wr1 = (const float*)d_in[17];
  const float* gr1 = (const float*)d_in[18];
  const float* br1 = (const float*)d_in[19];
  const float* Wr2 = (const float*)d_in[20];
  const float* gr2 = (const float*)d_in[21];
  const float* br2 = (const float*)d_in[22];
  const float* Wr3 = (const float*)d_in[23];
  const float* br3 = (const float*)d_in[24];

  if (ws_size < WS_NEED) return;

  char* ws = (char*)d_ws;
  u32* keys = (u32*)(ws + OF_KEYS);
  float* tbox = (float*)(ws + OF_TBOX);
  float* tsc  = (float*)(ws + OF_TSC);
  float* bx1 = (float*)(ws + OF_BX1);
  float* bx2 = (float*)(ws + OF_BX2);
  float* by1 = (float*)(ws + OF_BY1);
  float* by2 = (float*)(ws + OF_BY2);
  float* bar = (float*)(ws + OF_BAR);
  u32* mask = (u32*)(ws + OF_MASK);
  float* roisb = (float*)(ws + OF_ROIS);
  float* rscb  = (float*)(ws + OF_RSC);
  u32* Bsw = (u32*)(ws + OF_BSW);
  float* part = (float*)(ws + OF_PART);

  k_fatA<<<868, 1024, 0, stream>>>(rpn_cls, rpn_box, Ws1, keys, tbox, tsc,
                                   bx1, bx2, by1, by2, bar, Bsw);
  k_fatB<<<768, 256, 0, stream>>>(pooled, Bsw, part, bx1, bx2, by1, by2, bar, mask);
  k_nms<<<4, 64, 0, stream>>>(mask, tbox, tsc, roisb, rscb);
  k_chain<<<256, 512, 0, stream>>>(part, Ws2, Wc1, Wc2, Wr1, Wr2,
                                   g1, b1, g2, b2, gc1, bc1, gc2, bc2,
                                   gr1, br1, gr2, br2, Wc3, bc3, Wr3, br3,
                                   roisb, rscb, (float*)d_out);
}

// Round 10
// 269.609 us; speedup vs baseline: 1.4653x; 1.4653x over previous
//
#include <hip/hip_runtime.h>
#include <cstdint>

typedef unsigned int u32;
typedef unsigned long long u64;
typedef unsigned short u16;

#define BATCH 4
#define A_CNT 70400
#define FEAT 27648
#define KSPLIT 16
#define KCHUNK 1728          // FEAT/KSPLIT
#define NTILE_IT 27          // KCHUNK/64

typedef __attribute__((ext_vector_type(8))) short bf16x8;
typedef __attribute__((ext_vector_type(4))) float f32x4;
typedef __attribute__((ext_vector_type(4))) u32 u32x4;

// ---------------- workspace layout ----------------
constexpr size_t OF_KEYS = 0;                         // 4*70400*4 = 1126400
constexpr size_t OF_TBOX = OF_KEYS + 1126400;         // 114688
constexpr size_t OF_TSC  = OF_TBOX + 114688;          // 16384
constexpr size_t OF_BX1  = OF_TSC + 16384;
constexpr size_t OF_BX2  = OF_BX1 + 16384;
constexpr size_t OF_BY1  = OF_BX2 + 16384;
constexpr size_t OF_BY2  = OF_BY1 + 16384;
constexpr size_t OF_BAR  = OF_BY2 + 16384;
constexpr size_t OF_MASK = OF_BAR + 16384;            // 524288
constexpr size_t OF_ROIS = OF_MASK + 524288;          // 57344
constexpr size_t OF_RSC  = OF_ROIS + 57344;           // 8192
constexpr size_t OF_BSW  = OF_RSC + 8192;             // 14155776
constexpr size_t OF_PART = OF_BSW + 14155776;         // 33554432
constexpr size_t WS_NEED = OF_PART + 33554432;

// ---------------- helpers ----------------
__device__ __forceinline__ u32 keyOf(float f) {
  u32 u = __float_as_uint(f);
  return (u & 0x80000000u) ? ~u : (u | 0x80000000u);
}
__device__ __forceinline__ float keyToF(u32 k) {
  u32 u = (k & 0x80000000u) ? (k ^ 0x80000000u) : ~k;
  return __uint_as_float(u);
}
__device__ __forceinline__ u16 f2bf(float f) {   // RNE f32 -> bf16
  u32 u = __float_as_uint(f);
  u32 r = 0x7FFFu + ((u >> 16) & 1u);
  return (u16)((u + r) >> 16);
}
__device__ __forceinline__ void gload_lds16(const void* g, void* l) {
  auto gp = reinterpret_cast<const __attribute__((address_space(1))) unsigned int*>(
      reinterpret_cast<uintptr_t>(g));
  auto lp = reinterpret_cast<__attribute__((address_space(3))) unsigned int*>(
      reinterpret_cast<uintptr_t>(l));
  __builtin_amdgcn_global_load_lds(gp, lp, 16, 0, 0);
}
__device__ __forceinline__ u64 shflx64(u64 v, int m) {
  u32 lo = (u32)v, hi = (u32)(v >> 32);
  lo = __shfl_xor(lo, m, 64);
  hi = __shfl_xor(hi, m, 64);
  return ((u64)hi << 32) | lo;
}

// ---------------- fatA: blocks 0-863 Bsw prep; 864-1138 wide keygen (no atomics) ----------------
__global__ __launch_bounds__(1024) void k_fatA(const float* __restrict__ cls,
    const float* __restrict__ Ws1, u32* __restrict__ keys, u32* __restrict__ Bsw)
{
  int bid = blockIdx.x;
  int t = threadIdx.x;
  if (bid < 864) {
    // ---- Bsw prep: Ws1 -> swizzled bf16 tiles ----
    u32 w = (u32)bid * 1024u + t;        // u32x4 index (884736 total)
    u32 tile = w >> 11;                  // 2048 u32x4 per 32KB tile
    u32 rem = w & 2047u;
    u32 n = rem >> 3;                    // row 0..255
    u32 pq = (rem & 7u) << 4;            // 16B-aligned byte pos in row
    u32 q0 = pq ^ ((n & 7u) << 4);       // inverse-swizzled logical byte
    u32 col0 = tile * 64u + (q0 >> 1);
    const float* src = Ws1 + (size_t)n * FEAT + col0;
    float4 f0 = *(const float4*)src;
    float4 f1 = *(const float4*)(src + 4);
    u32x4 o;
    o.x = (u32)f2bf(f0.x) | ((u32)f2bf(f0.y) << 16);
    o.y = (u32)f2bf(f0.z) | ((u32)f2bf(f0.w) << 16);
    o.z = (u32)f2bf(f1.x) | ((u32)f2bf(f1.y) << 16);
    o.w = (u32)f2bf(f1.z) | ((u32)f2bf(f1.w) << 16);
    ((u32x4*)Bsw)[w] = o;
    return;
  }
  // ---- wide keygen: 275 blocks x 1024 = 281600 exactly ----
  u32 g = (u32)(bid - 864) * 1024u + t;
  float s0 = cls[(size_t)g * 3 + 0];
  float s1 = cls[(size_t)g * 3 + 1];
  float s2 = cls[(size_t)g * 3 + 2];
  keys[g] = keyOf(fmaxf(s0, fmaxf(s1, s2)));
}

// ---------------- prop: per-batch binary-search threshold (registers, no atomics)
//                  + aggregated compact + hybrid bitonic sort + NMS geometry ----------------
__global__ __launch_bounds__(1024) void k_prop(const u32* __restrict__ keys,
    const float* __restrict__ boxes, float* __restrict__ tbox, float* __restrict__ tsc,
    float* __restrict__ bx1, float* __restrict__ bx2, float* __restrict__ by1,
    float* __restrict__ by2, float* __restrict__ bar)
{
  int b = blockIdx.x, t = threadIdx.x;
  int lane = t & 63, wv = t >> 6;
  const u32* kb = keys + (size_t)b * A_CNT;
  __shared__ u64 s[2048];
  __shared__ u32 partials[16];
  __shared__ u32 cc;
  // cache hi-16 of this thread's 69 keys in 35 packed regs (ALL static indexing)
  u32 h[35];
#pragma unroll
  for (int j = 0; j < 35; ++j) {
    int g0 = t + ((2 * j) << 10);
    int g1 = t + ((2 * j + 1) << 10);
    u32 a = (g0 < A_CNT) ? (kb[g0] >> 16) : 0u;
    u32 c2 = (g1 < A_CNT) ? (kb[g1] >> 16) : 0u;
    h[j] = a | (c2 << 16);
  }
  if (t == 0) cc = 0u;
  // binary search: largest T with count(hi16 >= T) >= 1024  (== old suffix-scan select)
  u32 lo = 0, hi = 65536;
  while (hi - lo > 1) {
    u32 mid = (lo + hi) >> 1;
    u32 c = 0;
#pragma unroll
    for (int j = 0; j < 35; ++j) {
      c += ((h[j] & 0xFFFFu) >= mid) ? 1u : 0u;
      c += ((h[j] >> 16) >= mid) ? 1u : 0u;
    }
#pragma unroll
    for (int o = 32; o > 0; o >>= 1) c += __shfl_xor(c, o, 64);
    __syncthreads();
    if (lane == 0) partials[wv] = c;
    __syncthreads();
    u32 tot = 0;
#pragma unroll
    for (int w2 = 0; w2 < 16; ++w2) tot += partials[w2];
    if (tot >= 1024u) lo = mid; else hi = mid;
  }
  u32 kth = lo;
  __syncthreads();
  // aggregated compaction (order-independent; sort canonicalizes)
#pragma unroll 1
  for (int i = 0; i < 69; ++i) {
    int g = t + (i << 10);
    u32 k = (g < A_CNT) ? kb[g] : 0u;
    bool pass = (g < A_CNT) && ((k >> 16) >= kth);
    u64 mm = __ballot(pass);
    if (mm) {
      int leader = __ffsll((unsigned long long)mm) - 1;
      u32 base = 0;
      if (lane == leader) base = atomicAdd(&cc, (u32)__popcll(mm));
      base = __shfl(base, leader, 64);
      if (pass) {
        u32 pos = base + (u32)__popcll(mm & ((1ull << lane) - 1ull));
        if (pos < 2048u) s[pos] = ((u64)k << 32) | (u32)(~(u32)g);
      }
    }
  }
  __syncthreads();
  u32 m = cc; if (m > 2048u) m = 2048u;
  for (int e = t; e < 2048; e += 1024) if (e >= (int)m) s[e] = 0ull;
  __syncthreads();
  // ---- hybrid bitonic sort 2048 desc: reg levels (shfl) + LDS passes ----
  {
    u64 v0 = s[2 * t], v1 = s[2 * t + 1];
#pragma unroll
    for (u32 k = 2; k <= 128; k <<= 1) {
      bool desc = ((t & (k >> 1)) == 0);
#pragma unroll
      for (u32 j = (k >> 1); j >= 2; j >>= 1) {
        u32 mmk = j >> 1;
        u64 p0 = shflx64(v0, mmk);
        u64 p1 = shflx64(v1, mmk);
        bool up = ((t & mmk) == 0);
        bool mx = (desc == up);
        v0 = mx ? (v0 > p0 ? v0 : p0) : (v0 < p0 ? v0 : p0);
        v1 = mx ? (v1 > p1 ? v1 : p1) : (v1 < p1 ? v1 : p1);
      }
      if (desc ? (v0 < v1) : (v0 > v1)) { u64 tmp = v0; v0 = v1; v1 = tmp; }
    }
    s[2 * t] = v0; s[2 * t + 1] = v1;
    __syncthreads();
    for (u32 k = 256; k <= 2048; k <<= 1) {
      for (u32 j = k >> 1; j >= 128; j >>= 1) {
        for (int e = t; e < 2048; e += 1024) {
          u32 p = (u32)e ^ j;
          if (p > (u32)e) {
            bool d2 = ((e & k) == 0);
            u64 x = s[e], y = s[p];
            if (d2 ? (x < y) : (x > y)) { s[e] = y; s[p] = x; }
          }
        }
        __syncthreads();
      }
      u64 v0 = s[2 * t], v1 = s[2 * t + 1];
      bool desc = ((t & (k >> 1)) == 0);
#pragma unroll
      for (u32 j = 64; j >= 2; j >>= 1) {
        u32 mmk = j >> 1;
        u64 p0 = shflx64(v0, mmk);
        u64 p1 = shflx64(v1, mmk);
        bool up = ((t & mmk) == 0);
        bool mx = (desc == up);
        v0 = mx ? (v0 > p0 ? v0 : p0) : (v0 < p0 ? v0 : p0);
        v1 = mx ? (v1 > p1 ? v1 : p1) : (v1 < p1 ? v1 : p1);
      }
      if (desc ? (v0 < v1) : (v0 > v1)) { u64 tmp = v0; v0 = v1; v1 = tmp; }
      s[2 * t] = v0; s[2 * t + 1] = v1;
      __syncthreads();
    }
  }
  // ---- geometry tail ----
  u64 comp = s[t];
  u32 kk = (u32)(comp >> 32);
  u32 a = ~(u32)(comp & 0xFFFFFFFFull);
  int o = b * 1024 + t;
  tsc[o] = keyToF(kk);
  const float* bp = boxes + ((size_t)b * A_CNT + a) * 7;
  float x = bp[0], y = bp[1], z = bp[2], dx = bp[3], dy = bp[4], dz = bp[5], rr = bp[6];
  float* tb = tbox + (size_t)o * 7;
  tb[0] = x; tb[1] = y; tb[2] = z; tb[3] = dx; tb[4] = dy; tb[5] = dz; tb[6] = rr;
  {
#pragma clang fp contract(off)
    bx1[o] = x - 0.5f * dx; bx2[o] = x + 0.5f * dx;
    by1[o] = y - 0.5f * dy; by2[o] = y + 0.5f * dy;
    bar[o] = dx * dy;
  }
}

// ---------------- fatB: blocks 0-511 GEMM1 (XCD-swizzled split-K); 512-767 IoU masks ----------------
__global__ __launch_bounds__(256) void k_fatB(const float* __restrict__ A,
    const u32* __restrict__ Bsw, float* __restrict__ part,
    const float* __restrict__ bx1, const float* __restrict__ bx2,
    const float* __restrict__ by1, const float* __restrict__ by2,
    const float* __restrict__ bar, u32* __restrict__ mask)
{
  __shared__ u32x4 Alds4[64 * 8];    // 8 KB
  __shared__ u32x4 Blds4[256 * 8];   // 32 KB
  int bid = blockIdx.x;
  if (bid >= 512) {
    int mi = bid - 512;
    int b = mi >> 6;
    int cbk = (mi >> 2) & 15;
    int rb0 = (mi & 3) * 4;
    int tt = threadIdx.x;
    int rbi = tt >> 6, ln = tt & 63;
    int r = (rb0 + rbi) * 64 + ln;
    int o = b * 1024, jc0 = cbk * 64;
    __shared__ float cx1[64], cx2[64], cy1[64], cy2[64], car[64];
    if (tt < 64) {
      cx1[tt] = bx1[o + jc0 + tt]; cx2[tt] = bx2[o + jc0 + tt];
      cy1[tt] = by1[o + jc0 + tt]; cy2[tt] = by2[o + jc0 + tt];
      car[tt] = bar[o + jc0 + tt];
    }
    __syncthreads();
    float rx1 = bx1[o + r], rx2 = bx2[o + r], ry1 = by1[o + r], ry2 = by2[o + r], rar = bar[o + r];
    u32 w0 = 0, w1 = 0;
    {
#pragma clang fp contract(off)
      for (int c = 0; c < 64; ++c) {
        int jc = jc0 + c;
        float iw = fminf(rx2, cx2[c]) - fmaxf(rx1, cx1[c]); iw = fmaxf(iw, 0.0f);
        float ih = fminf(ry2, cy2[c]) - fmaxf(ry1, cy1[c]); ih = fmaxf(ih, 0.0f);
        float inter = iw * ih;
        float den = fmaxf(rar + car[c] - inter, 1e-6f);
        float iou = inter / den;
        if ((iou > 0.7f) && (jc > r)) {
          if (c < 32) w0 |= 1u << c; else w1 |= 1u << (c - 32);
        }
      }
    }
    mask[((size_t)(o + r)) * 32 + cbk * 2 + 0] = w0;
    mask[((size_t)(o + r)) * 32 + cbk * 2 + 1] = w1;
    return;
  }
  // ---- GEMM path ----
  char* Alds = (char*)Alds4;
  char* Blds = (char*)Blds4;
  int q = bid >> 3;                    // 0..63
  int ks = (bid & 7) * 2 + (q >> 5);   // XCD-local K-chunk
  int mt = q & 31;
  int tid = threadIdx.x, lane = tid & 63, wv = tid >> 6;

  f32x4 acc[4][4];
#pragma unroll
  for (int i = 0; i < 4; ++i)
#pragma unroll
    for (int j = 0; j < 4; ++j) acc[i][j] = (f32x4){0.f, 0.f, 0.f, 0.f};

  int am = tid >> 2;
  int ak = (tid & 3) * 16;
  const float* ap_base = A + ((size_t)(mt * 64 + am)) * FEAT + (size_t)ks * KCHUNK + ak;
  int asw = (am & 7) << 4;
  int ac0 = (tid & 3) * 32;
  char* aw0 = Alds + am * 128 + ((ac0) ^ asw);
  char* aw1 = Alds + am * 128 + ((ac0 + 16) ^ asw);
  const char* bsrc_base = (const char*)Bsw + ((size_t)(ks * NTILE_IT)) * 32768 + (wv * 8) * 1024 + lane * 16;
  char* bdst_base = Blds + (wv * 8) * 1024;

  int row16 = lane & 15, kgrp = lane >> 4;
  int aoff[4][2], boff[4][2];
#pragma unroll
  for (int ksub = 0; ksub < 2; ++ksub) {
    int qq = ksub * 64 + kgrp * 16;
#pragma unroll
    for (int mf = 0; mf < 4; ++mf) {
      int row = mf * 16 + row16;
      aoff[mf][ksub] = row * 128 + (qq ^ ((row & 7) << 4));
    }
#pragma unroll
    for (int nf = 0; nf < 4; ++nf) {
      int n = wv * 64 + nf * 16 + row16;
      boff[nf][ksub] = n * 128 + (qq ^ ((n & 7) << 4));
    }
  }

  for (int it = 0; it < NTILE_IT; ++it) {
    const float4* ap = (const float4*)(ap_base + it * 64);
    float4 f0 = ap[0], f1 = ap[1], f2 = ap[2], f3 = ap[3];
    u32x4 c0, c1;
    c0.x = (u32)f2bf(f0.x) | ((u32)f2bf(f0.y) << 16);
    c0.y = (u32)f2bf(f0.z) | ((u32)f2bf(f0.w) << 16);
    c0.z = (u32)f2bf(f1.x) | ((u32)f2bf(f1.y) << 16);
    c0.w = (u32)f2bf(f1.z) | ((u32)f2bf(f1.w) << 16);
    c1.x = (u32)f2bf(f2.x) | ((u32)f2bf(f2.y) << 16);
    c1.y = (u32)f2bf(f2.z) | ((u32)f2bf(f2.w) << 16);
    c1.z = (u32)f2bf(f3.x) | ((u32)f2bf(f3.y) << 16);
    c1.w = (u32)f2bf(f3.z) | ((u32)f2bf(f3.w) << 16);
    *(u32x4*)aw0 = c0;
    *(u32x4*)aw1 = c1;
    const char* bs = bsrc_base + (size_t)it * 32768;
#pragma unroll
    for (int i = 0; i < 8; ++i) gload_lds16(bs + i * 1024, bdst_base + i * 1024);
    __syncthreads();
    bf16x8 af[4][2], bfv[4][2];
#pragma unroll
    for (int ksub = 0; ksub < 2; ++ksub) {
#pragma unroll
      for (int mf = 0; mf < 4; ++mf) af[mf][ksub] = *(const bf16x8*)(Alds + aoff[mf][ksub]);
#pragma unroll
      for (int nf = 0; nf < 4; ++nf) bfv[nf][ksub] = *(const bf16x8*)(Blds + boff[nf][ksub]);
    }
#pragma unroll
    for (int ksub = 0; ksub < 2; ++ksub)
#pragma unroll
      for (int mf = 0; mf < 4; ++mf)
#pragma unroll
        for (int nf = 0; nf < 4; ++nf)
          acc[mf][nf] = __builtin_amdgcn_mfma_f32_16x16x32_bf16(af[mf][ksub], bfv[nf][ksub], acc[mf][nf], 0, 0, 0);
    __syncthreads();
  }
  float* pb = part + (size_t)ks * 524288;
#pragma unroll
  for (int mf = 0; mf < 4; ++mf) {
    int row = mt * 64 + mf * 16 + kgrp * 4;
#pragma unroll
    for (int nf = 0; nf < 4; ++nf) {
      int col = wv * 64 + nf * 16 + row16;
#pragma unroll
      for (int rr = 0; rr < 4; ++rr)
        pb[(size_t)(row + rr) * 256 + col] = acc[mf][nf][rr];
    }
  }
}

// ---------------- chunked sequential greedy NMS + compact to rois ----------------
__global__ __launch_bounds__(64) void k_nms(const u32* __restrict__ mask,
    const float* __restrict__ tbox, const float* __restrict__ tsc,
    float* __restrict__ rois, float* __restrict__ rsc)
{
  int b = blockIdx.x;
  int lane = threadIdx.x;
  int el = lane & 31;
  const u32* M = mask + (size_t)b * 1024 * 32;
  u32 R = 0;
  u32 cur[32], nxt[32];
#pragma unroll
  for (int i = 0; i < 32; ++i) cur[i] = M[(size_t)(i * 32 + el)];
#pragma unroll 1
  for (int c = 0; c < 32; ++c) {
    if (c < 31) {
      int nb = (c + 1) * 1024 + el;
#pragma unroll
      for (int i = 0; i < 32; ++i) nxt[i] = M[(size_t)(nb + i * 32)];
    }
    u32 w = R;
#pragma unroll
    for (int i = 0; i < 32; ++i) w |= ((w >> i) & 1u) ? 0u : cur[i];
    u32 wfin = __shfl(w, c, 64);
#pragma unroll
    for (int i = 0; i < 32; ++i) R |= ((wfin >> i) & 1u) ? 0u : cur[i];
#pragma unroll
    for (int i = 0; i < 32; ++i) cur[i] = nxt[i];
  }
  u32 keepw = (lane < 32) ? ~R : 0u;
  int c = __popc(keepw);
  int pre = c;
  for (int d = 1; d < 64; d <<= 1) {
    int v = __shfl_up(pre, d, 64);
    if (lane >= d) pre += v;
  }
  int total = __shfl(pre, 31, 64);
  int base = pre - c;
  if (lane < 32) {
    u32 w = keepw;
    int rank = base;
    while (w) {
      int bit = __ffs(w) - 1;
      w &= w - 1;
      if (rank < 512) {
        int r = lane * 32 + bit;
        const float* tb = tbox + ((size_t)b * 1024 + r) * 7;
        float* rp = rois + ((size_t)b * 512 + rank) * 7;
        rp[0] = tb[0]; rp[1] = tb[1]; rp[2] = tb[2]; rp[3] = tb[3];
        rp[4] = tb[4]; rp[5] = tb[5]; rp[6] = tb[6];
        rsc[b * 512 + rank] = tsc[b * 1024 + r];
      }
      rank++;
    }
  }
  for (int z = total + lane; z < 512; z += 64) {
    float* rp = rois + ((size_t)b * 512 + z) * 7;
    rp[0] = rp[1] = rp[2] = rp[3] = rp[4] = rp[5] = rp[6] = 0.0f;
    rsc[b * 512 + z] = 0.0f;
  }
}

// ---------------- one 256x256 layer (4 rows per thread-half) + BN + ReLU ----------------
__device__ __forceinline__ void layer4(const float (*IN)[256], const float* __restrict__ W,
    const float* __restrict__ g, const float* __restrict__ bb, float (*OUT)[256], int t, int h)
{
  float acc[4] = {0, 0, 0, 0};
  const float* Wrow = W + (size_t)t * 256;
  for (int k = 0; k < 256; k += 4) {
    float4 w4 = *(const float4*)&Wrow[k];
#pragma unroll
    for (int r = 0; r < 4; ++r) {
      float4 xv = *(const float4*)&IN[h * 4 + r][k];
      acc[r] = fmaf(xv.x, w4.x, acc[r]);
      acc[r] = fmaf(xv.y, w4.y, acc[r]);
      acc[r] = fmaf(xv.z, w4.z, acc[r]);
      acc[r] = fmaf(xv.w, w4.w, acc[r]);
    }
  }
  float sc = g[t] / sqrtf(1.0f + 1e-5f);
  float bv = bb[t];
#pragma unroll
  for (int r = 0; r < 4; ++r)
    OUT[h * 4 + r][t] = fmaxf(fmaf(acc[r], sc, bv), 0.0f);
}

// ---------------- fused head chain (512 threads) ----------------
__global__ __launch_bounds__(512) void k_chain(const float* __restrict__ part,
    const float* __restrict__ Ws2, const float* __restrict__ Wc1, const float* __restrict__ Wc2,
    const float* __restrict__ Wr1, const float* __restrict__ Wr2,
    const float* __restrict__ g1, const float* __restrict__ b1,
    const float* __restrict__ g2, const float* __restrict__ b2,
    const float* __restrict__ gc1, const float* __restrict__ bc1,
    const float* __restrict__ gc2, const float* __restrict__ bc2,
    const float* __restrict__ gr1, const float* __restrict__ br1,
    const float* __restrict__ gr2, const float* __restrict__ br2,
    const float* __restrict__ Wc3, const float* __restrict__ bc3,
    const float* __restrict__ Wr3, const float* __restrict__ br3,
    const float* __restrict__ rois, const float* __restrict__ rsc,
    float* __restrict__ out)
{
  int bid = blockIdx.x, tid = threadIdx.x;
  int t = tid & 255, h = tid >> 8;        // h: row-half (rows h*4..h*4+3)
  __shared__ __align__(16) float bufX[8][256];
  __shared__ __align__(16) float bufY[8][256];
  __shared__ __align__(16) float bufC[8][256];
  __shared__ __align__(16) float bufR[8][256];
  __shared__ float hd[64];
  {
    float sc = g1[t] / sqrtf(1.0f + 1e-5f);
    float bv = b1[t];
#pragma unroll
    for (int r = 0; r < 4; ++r) {
      int row = h * 4 + r;
      float s = 0.f;
#pragma unroll
      for (int ks = 0; ks < KSPLIT; ++ks)
        s += part[(size_t)ks * 524288 + (size_t)(bid * 8 + row) * 256 + t];
      bufX[row][t] = fmaxf(fmaf(s, sc, bv), 0.0f);
    }
  }
  __syncthreads();
  layer4(bufX, Ws2, g2, b2, bufY, t, h);          // x2
  __syncthreads();
  layer4(bufY, Wc1, gc1, bc1, bufC, t, h);        // c1
  layer4(bufY, Wr1, gr1, br1, bufR, t, h);        // r1
  __syncthreads();
  layer4(bufC, Wc2, gc2, bc2, bufX, t, h);        // c2 -> bufX
  layer4(bufR, Wr2, gr2, br2, bufY, t, h);        // r2 -> bufY
  __syncthreads();
  int wv = tid >> 6, ln = tid & 63;
  for (int task = wv; task < 64; task += 8) {
    float p;
    if (task < 8) {
      float4 yv = *(const float4*)&bufX[task][ln * 4];
      float4 w4 = ((const float4*)Wc3)[ln];
      p = yv.x * w4.x + yv.y * w4.y + yv.z * w4.z + yv.w * w4.w;
    } else {
      int i = task - 8, row = i / 7, j = i % 7;
      float4 yv = *(const float4*)&bufY[row][ln * 4];
      float4 w4 = ((const float4*)(Wr3 + j * 256))[ln];
      p = yv.x * w4.x + yv.y * w4.y + yv.z * w4.z + yv.w * w4.w;
    }
#pragma unroll
    for (int off = 32; off > 0; off >>= 1) p += __shfl_xor(p, off, 64);
    if (ln == 0) hd[task] = p;
  }
  __syncthreads();
  if (tid < 8) {
    int m = bid * 8 + tid;
    float clsv = hd[tid] + bc3[0];
    float rg[7];
#pragma unroll
    for (int j = 0; j < 7; ++j) rg[j] = hd[8 + tid * 7 + j] + br3[j];
    const float* R = rois + (size_t)m * 7;
    float rx = R[0], ry = R[1], rz = R[2], dxa = R[3], dya = R[4], dza = R[5], ra = R[6];
    float diag = sqrtf(dxa * dxa + dya * dya);
    float x = rg[0] * diag, y = rg[1] * diag, z = rg[2] * dza;
    float ex = expf(rg[3]) * dxa, ey = expf(rg[4]) * dya, ez = expf(rg[5]) * dza;
    float hr = rg[6] + ra;
    float cc = cosf(ra), sn = sinf(ra);
    float xr = x * cc - y * sn, yr = x * sn + y * cc;
    float* O = out + (size_t)m * 9;
    O[0] = clsv; O[1] = xr + rx; O[2] = yr + ry; O[3] = z + rz;
    O[4] = ex; O[5] = ey; O[6] = ez; O[7] = hr; O[8] = rsc[m];
  }
}

// ---------------- launch ----------------
extern "C" void kernel_launch(void* const* d_in, const int* in_sizes, int n_in,
                              void* d_out, int out_size, void* d_ws, size_t ws_size,
                              hipStream_t stream)
{
  const float* rpn_box = (const float*)d_in[0];
  const float* rpn_cls = (const float*)d_in[1];
  const float* pooled  = (const float*)d_in[2];
  const float* Ws1 = (const float*)d_in[3];
  const float* g1  = (const float*)d_in[4];
  const float* b1  = (const float*)d_in[5];
  const float* Ws2 = (const float*)d_in[6];
  const float* g2  = (const float*)d_in[7];
  const float* b2  = (const float*)d_in[8];
  const float* Wc1 = (const float*)d_in[9];
  const float* gc1 = (const float*)d_in[10];
  const float* bc1 = (const float*)d_in[11];
  const float* Wc2 = (const float*)d_in[12];
  const float* gc2 = (const float*)d_in[13];
  const float* bc2 = (const float*)d_in[14];
  const float* Wc3 = (const float*)d_in[15];
  const float* bc3 = (const float*)d_in[16];
  const float* Wr1 = (const float*)d_in[17];
  const float* gr1 = (const float*)d_in[18];
  const float* br1 = (const float*)d_in[19];
  const float* Wr2 = (const float*)d_in[20];
  const float* gr2 = (const float*)d_in[21];
  const float* br2 = (const float*)d_in[22];
  const float* Wr3 = (const float*)d_in[23];
  const float* br3 = (const float*)d_in[24];

  if (ws_size < WS_NEED) return;

  char* ws = (char*)d_ws;
  u32* keys = (u32*)(ws + OF_KEYS);
  float* tbox = (float*)(ws + OF_TBOX);
  float* tsc  = (float*)(ws + OF_TSC);
  float* bx1 = (float*)(ws + OF_BX1);
  float* bx2 = (float*)(ws + OF_BX2);
  float* by1 = (float*)(ws + OF_BY1);
  float* by2 = (float*)(ws + OF_BY2);
  float* bar = (float*)(ws + OF_BAR);
  u32* mask = (u32*)(ws + OF_MASK);
  float* roisb = (float*)(ws + OF_ROIS);
  float* rscb  = (float*)(ws + OF_RSC);
  u32* Bsw = (u32*)(ws + OF_BSW);
  float* part = (float*)(ws + OF_PART);

  k_fatA<<<1139, 1024, 0, stream>>>(rpn_cls, Ws1, keys, Bsw);
  k_prop<<<4, 1024, 0, stream>>>(keys, rpn_box, tbox, tsc, bx1, bx2, by1, by2, bar);
  k_fatB<<<768, 256, 0, stream>>>(pooled, Bsw, part, bx1, bx2, by1, by2, bar, mask);
  k_nms<<<4, 64, 0, stream>>>(mask, tbox, tsc, roisb, rscb);
  k_chain<<<256, 512, 0, stream>>>(part, Ws2, Wc1, Wc2, Wr1, Wr2,
                                   g1, b1, g2, b2, gc1, bc1, gc2, bc2,
                                   gr1, br1, gr2, br2, Wc3, bc3, Wr3, br3,
                                   roisb, rscb, (float*)d_out);
}

// Round 11
// 259.722 us; speedup vs baseline: 1.5211x; 1.0381x over previous
//
#include <hip/hip_runtime.h>
#include <cstdint>

typedef unsigned int u32;
typedef unsigned long long u64;
typedef unsigned short u16;

#define BATCH 4
#define A_CNT 70400
#define FEAT 27648
#define KSPLIT 16
#define KCHUNK 1728          // FEAT/KSPLIT
#define NTILE_IT 27          // KCHUNK/64

typedef __attribute__((ext_vector_type(8))) short bf16x8;
typedef __attribute__((ext_vector_type(4))) float f32x4;
typedef __attribute__((ext_vector_type(4))) u32 u32x4;

// ---------------- workspace layout ----------------
constexpr size_t OF_KEYS = 0;                         // 4*70400*4 = 1126400
constexpr size_t OF_TBOX = OF_KEYS + 1126400;         // 114688
constexpr size_t OF_TSC  = OF_TBOX + 114688;          // 16384
constexpr size_t OF_BX1  = OF_TSC + 16384;
constexpr size_t OF_BX2  = OF_BX1 + 16384;
constexpr size_t OF_BY1  = OF_BX2 + 16384;
constexpr size_t OF_BY2  = OF_BY1 + 16384;
constexpr size_t OF_BAR  = OF_BY2 + 16384;
constexpr size_t OF_MASK = OF_BAR + 16384;            // 524288
constexpr size_t OF_ROIS = OF_MASK + 524288;          // 57344
constexpr size_t OF_RSC  = OF_ROIS + 57344;           // 8192
constexpr size_t OF_BSW  = OF_RSC + 8192;             // 14155776
constexpr size_t OF_PART = OF_BSW + 14155776;         // 33554432
constexpr size_t WS_NEED = OF_PART + 33554432;

// ---------------- helpers ----------------
__device__ __forceinline__ u32 keyOf(float f) {
  u32 u = __float_as_uint(f);
  return (u & 0x80000000u) ? ~u : (u | 0x80000000u);
}
__device__ __forceinline__ float keyToF(u32 k) {
  u32 u = (k & 0x80000000u) ? (k ^ 0x80000000u) : ~k;
  return __uint_as_float(u);
}
__device__ __forceinline__ u16 f2bf(float f) {   // RNE f32 -> bf16
  u32 u = __float_as_uint(f);
  u32 r = 0x7FFFu + ((u >> 16) & 1u);
  return (u16)((u + r) >> 16);
}
__device__ __forceinline__ void gload_lds16(const void* g, void* l) {
  auto gp = reinterpret_cast<const __attribute__((address_space(1))) unsigned int*>(
      reinterpret_cast<uintptr_t>(g));
  auto lp = reinterpret_cast<__attribute__((address_space(3))) unsigned int*>(
      reinterpret_cast<uintptr_t>(l));
  __builtin_amdgcn_global_load_lds(gp, lp, 16, 0, 0);
}
__device__ __forceinline__ u64 shflx64(u64 v, int m) {
  u32 lo = (u32)v, hi = (u32)(v >> 32);
  lo = __shfl_xor(lo, m, 64);
  hi = __shfl_xor(hi, m, 64);
  return ((u64)hi << 32) | lo;
}

// ---------------- fatA: blocks 0-863 Bsw prep; 864-1138 wide keygen (no atomics) ----------------
__global__ __launch_bounds__(1024) void k_fatA(const float* __restrict__ cls,
    const float* __restrict__ Ws1, u32* __restrict__ keys, u32* __restrict__ Bsw)
{
  int bid = blockIdx.x;
  int t = threadIdx.x;
  if (bid < 864) {
    // ---- Bsw prep: Ws1 -> swizzled bf16 tiles ----
    u32 w = (u32)bid * 1024u + t;        // u32x4 index (884736 total)
    u32 tile = w >> 11;                  // 2048 u32x4 per 32KB tile
    u32 rem = w & 2047u;
    u32 n = rem >> 3;                    // row 0..255
    u32 pq = (rem & 7u) << 4;            // 16B-aligned byte pos in row
    u32 q0 = pq ^ ((n & 7u) << 4);       // inverse-swizzled logical byte
    u32 col0 = tile * 64u + (q0 >> 1);
    const float* src = Ws1 + (size_t)n * FEAT + col0;
    float4 f0 = *(const float4*)src;
    float4 f1 = *(const float4*)(src + 4);
    u32x4 o;
    o.x = (u32)f2bf(f0.x) | ((u32)f2bf(f0.y) << 16);
    o.y = (u32)f2bf(f0.z) | ((u32)f2bf(f0.w) << 16);
    o.z = (u32)f2bf(f1.x) | ((u32)f2bf(f1.y) << 16);
    o.w = (u32)f2bf(f1.z) | ((u32)f2bf(f1.w) << 16);
    ((u32x4*)Bsw)[w] = o;
    return;
  }
  // ---- wide keygen: 275 blocks x 1024 = 281600 exactly ----
  u32 g = (u32)(bid - 864) * 1024u + t;
  float s0 = cls[(size_t)g * 3 + 0];
  float s1 = cls[(size_t)g * 3 + 1];
  float s2 = cls[(size_t)g * 3 + 2];
  keys[g] = keyOf(fmaxf(s0, fmaxf(s1, s2)));
}

// ---------------- prop: per-batch binary-search threshold (registers, no atomics)
//                  + aggregated compact + hybrid bitonic sort + NMS geometry ----------------
__global__ __launch_bounds__(1024) void k_prop(const u32* __restrict__ keys,
    const float* __restrict__ boxes, float* __restrict__ tbox, float* __restrict__ tsc,
    float* __restrict__ bx1, float* __restrict__ bx2, float* __restrict__ by1,
    float* __restrict__ by2, float* __restrict__ bar)
{
  int b = blockIdx.x, t = threadIdx.x;
  int lane = t & 63, wv = t >> 6;
  const u32* kb = keys + (size_t)b * A_CNT;
  __shared__ u64 s[2048];
  __shared__ u32 partials[16];
  __shared__ u32 cc;
  // cache hi-16 of this thread's 69 keys in 35 packed regs (ALL static indexing)
  u32 h[35];
#pragma unroll
  for (int j = 0; j < 35; ++j) {
    int g0 = t + ((2 * j) << 10);
    int g1 = t + ((2 * j + 1) << 10);
    u32 a = (g0 < A_CNT) ? (kb[g0] >> 16) : 0u;
    u32 c2 = (g1 < A_CNT) ? (kb[g1] >> 16) : 0u;
    h[j] = a | (c2 << 16);
  }
  if (t == 0) cc = 0u;
  // binary search: largest T with count(hi16 >= T) >= 1024
  u32 lo = 0, hi = 65536;
  while (hi - lo > 1) {
    u32 mid = (lo + hi) >> 1;
    u32 c = 0;
#pragma unroll
    for (int j = 0; j < 35; ++j) {
      c += ((h[j] & 0xFFFFu) >= mid) ? 1u : 0u;
      c += ((h[j] >> 16) >= mid) ? 1u : 0u;
    }
#pragma unroll
    for (int o = 32; o > 0; o >>= 1) c += __shfl_xor(c, o, 64);
    __syncthreads();
    if (lane == 0) partials[wv] = c;
    __syncthreads();
    u32 tot = 0;
#pragma unroll
    for (int w2 = 0; w2 < 16; ++w2) tot += partials[w2];
    if (tot >= 1024u) lo = mid; else hi = mid;
  }
  u32 kth = lo;
  __syncthreads();
  // aggregated compaction (prefetched keys; order-independent, sort canonicalizes)
  u32 kc = kb[t];
#pragma unroll 1
  for (int i = 0; i < 69; ++i) {
    int g = t + (i << 10);
    u32 k = kc;
    if (i < 68) {
      int gn = t + ((i + 1) << 10);
      kc = (gn < A_CNT) ? kb[gn] : 0u;
    }
    bool pass = (g < A_CNT) && ((k >> 16) >= kth);
    u64 mm = __ballot(pass);
    if (mm) {
      int leader = __ffsll((unsigned long long)mm) - 1;
      u32 base = 0;
      if (lane == leader) base = atomicAdd(&cc, (u32)__popcll(mm));
      base = __shfl(base, leader, 64);
      if (pass) {
        u32 pos = base + (u32)__popcll(mm & ((1ull << lane) - 1ull));
        if (pos < 2048u) s[pos] = ((u64)k << 32) | (u32)(~(u32)g);
      }
    }
  }
  __syncthreads();
  u32 m = cc; if (m > 2048u) m = 2048u;
  for (int e = t; e < 2048; e += 1024) if (e >= (int)m) s[e] = 0ull;
  __syncthreads();
  // ---- hybrid bitonic sort 2048 desc: reg levels (shfl) + LDS passes ----
  {
    u64 v0 = s[2 * t], v1 = s[2 * t + 1];
#pragma unroll
    for (u32 k = 2; k <= 128; k <<= 1) {
      bool desc = ((t & (k >> 1)) == 0);
#pragma unroll
      for (u32 j = (k >> 1); j >= 2; j >>= 1) {
        u32 mmk = j >> 1;
        u64 p0 = shflx64(v0, mmk);
        u64 p1 = shflx64(v1, mmk);
        bool up = ((t & mmk) == 0);
        bool mx = (desc == up);
        v0 = mx ? (v0 > p0 ? v0 : p0) : (v0 < p0 ? v0 : p0);
        v1 = mx ? (v1 > p1 ? v1 : p1) : (v1 < p1 ? v1 : p1);
      }
      if (desc ? (v0 < v1) : (v0 > v1)) { u64 tmp = v0; v0 = v1; v1 = tmp; }
    }
    s[2 * t] = v0; s[2 * t + 1] = v1;
    __syncthreads();
    for (u32 k = 256; k <= 2048; k <<= 1) {
      for (u32 j = k >> 1; j >= 128; j >>= 1) {
        for (int e = t; e < 2048; e += 1024) {
          u32 p = (u32)e ^ j;
          if (p > (u32)e) {
            bool d2 = ((e & k) == 0);
            u64 x = s[e], y = s[p];
            if (d2 ? (x < y) : (x > y)) { s[e] = y; s[p] = x; }
          }
        }
        __syncthreads();
      }
      u64 v0 = s[2 * t], v1 = s[2 * t + 1];
      bool desc = ((t & (k >> 1)) == 0);
#pragma unroll
      for (u32 j = 64; j >= 2; j >>= 1) {
        u32 mmk = j >> 1;
        u64 p0 = shflx64(v0, mmk);
        u64 p1 = shflx64(v1, mmk);
        bool up = ((t & mmk) == 0);
        bool mx = (desc == up);
        v0 = mx ? (v0 > p0 ? v0 : p0) : (v0 < p0 ? v0 : p0);
        v1 = mx ? (v1 > p1 ? v1 : p1) : (v1 < p1 ? v1 : p1);
      }
      if (desc ? (v0 < v1) : (v0 > v1)) { u64 tmp = v0; v0 = v1; v1 = tmp; }
      s[2 * t] = v0; s[2 * t + 1] = v1;
      __syncthreads();
    }
  }
  // ---- geometry tail ----
  u64 comp = s[t];
  u32 kk = (u32)(comp >> 32);
  u32 a = ~(u32)(comp & 0xFFFFFFFFull);
  int o = b * 1024 + t;
  tsc[o] = keyToF(kk);
  const float* bp = boxes + ((size_t)b * A_CNT + a) * 7;
  float x = bp[0], y = bp[1], z = bp[2], dx = bp[3], dy = bp[4], dz = bp[5], rr = bp[6];
  float* tb = tbox + (size_t)o * 7;
  tb[0] = x; tb[1] = y; tb[2] = z; tb[3] = dx; tb[4] = dy; tb[5] = dz; tb[6] = rr;
  {
#pragma clang fp contract(off)
    bx1[o] = x - 0.5f * dx; bx2[o] = x + 0.5f * dx;
    by1[o] = y - 0.5f * dy; by2[o] = y + 0.5f * dy;
    bar[o] = dx * dy;
  }
}

// ---------------- fatB: blocks 0-511 GEMM1 (2-phase dbuf pipeline); 512-767 IoU masks ----------------
__global__ __launch_bounds__(256) void k_fatB(const float* __restrict__ A,
    const u32* __restrict__ Bsw, float* __restrict__ part,
    const float* __restrict__ bx1, const float* __restrict__ bx2,
    const float* __restrict__ by1, const float* __restrict__ by2,
    const float* __restrict__ bar, u32* __restrict__ mask)
{
  // 80 KB: A dbuf 2x8KB at [0,16384), B dbuf 2x32KB at [16384,81920) -> 2 blocks/CU
  __shared__ __align__(16) char smem[81920];
  int bid = blockIdx.x;
  if (bid >= 512) {
    // ---- mask path (aliases smem) ----
    int mi = bid - 512;
    int b = mi >> 6;
    int cbk = (mi >> 2) & 15;
    int rb0 = (mi & 3) * 4;
    int tt = threadIdx.x;
    int rbi = tt >> 6, ln = tt & 63;
    int r = (rb0 + rbi) * 64 + ln;
    int o = b * 1024, jc0 = cbk * 64;
    float* cx1 = (float*)(smem);
    float* cx2 = (float*)(smem + 256);
    float* cy1 = (float*)(smem + 512);
    float* cy2 = (float*)(smem + 768);
    float* car = (float*)(smem + 1024);
    if (tt < 64) {
      cx1[tt] = bx1[o + jc0 + tt]; cx2[tt] = bx2[o + jc0 + tt];
      cy1[tt] = by1[o + jc0 + tt]; cy2[tt] = by2[o + jc0 + tt];
      car[tt] = bar[o + jc0 + tt];
    }
    __syncthreads();
    float rx1 = bx1[o + r], rx2 = bx2[o + r], ry1 = by1[o + r], ry2 = by2[o + r], rar = bar[o + r];
    u32 w0 = 0, w1 = 0;
    {
#pragma clang fp contract(off)
      for (int c = 0; c < 64; ++c) {
        int jc = jc0 + c;
        float iw = fminf(rx2, cx2[c]) - fmaxf(rx1, cx1[c]); iw = fmaxf(iw, 0.0f);
        float ih = fminf(ry2, cy2[c]) - fmaxf(ry1, cy1[c]); ih = fmaxf(ih, 0.0f);
        float inter = iw * ih;
        float den = fmaxf(rar + car[c] - inter, 1e-6f);
        float iou = inter / den;
        if ((iou > 0.7f) && (jc > r)) {
          if (c < 32) w0 |= 1u << c; else w1 |= 1u << (c - 32);
        }
      }
    }
    mask[((size_t)(o + r)) * 32 + cbk * 2 + 0] = w0;
    mask[((size_t)(o + r)) * 32 + cbk * 2 + 1] = w1;
    return;
  }
  // ---- GEMM path: 2-phase double-buffered pipeline ----
  int q = bid >> 3;                    // 0..63
  int ks = (bid & 7) * 2 + (q >> 5);   // XCD-local K-chunk
  int mt = q & 31;
  int tid = threadIdx.x, lane = tid & 63, wv = tid >> 6;

  f32x4 acc[4][4];
#pragma unroll
  for (int i = 0; i < 4; ++i)
#pragma unroll
    for (int j = 0; j < 4; ++j) acc[i][j] = (f32x4){0.f, 0.f, 0.f, 0.f};

  int am = tid >> 2;
  int ak = (tid & 3) * 16;
  const float* ap_base = A + ((size_t)(mt * 64 + am)) * FEAT + (size_t)ks * KCHUNK + ak;
  int asw = (am & 7) << 4;
  int ac0 = (tid & 3) * 32;
  int awoff0 = am * 128 + (ac0 ^ asw);
  int awoff1 = am * 128 + ((ac0 + 16) ^ asw);
  const char* bsrc_base = (const char*)Bsw + ((size_t)(ks * NTILE_IT)) * 32768 + (wv * 8) * 1024 + lane * 16;
  int bdoff = (wv * 8) * 1024;         // wave-uniform LDS offset within B buffer

  int row16 = lane & 15, kgrp = lane >> 4;
  int aoff[4][2], boff[4][2];
#pragma unroll
  for (int ksub = 0; ksub < 2; ++ksub) {
    int qq = ksub * 64 + kgrp * 16;
#pragma unroll
    for (int mf = 0; mf < 4; ++mf) {
      int row = mf * 16 + row16;
      aoff[mf][ksub] = row * 128 + (qq ^ ((row & 7) << 4));
    }
#pragma unroll
    for (int nf = 0; nf < 4; ++nf) {
      int n = wv * 64 + nf * 16 + row16;
      boff[nf][ksub] = n * 128 + (qq ^ ((n & 7) << 4));
    }
  }

  // prologue: stage tile 0 into buffer 0
  {
    const float4* ap = (const float4*)ap_base;
    float4 f0 = ap[0], f1 = ap[1], f2 = ap[2], f3 = ap[3];
    u32x4 c0, c1;
    c0.x = (u32)f2bf(f0.x) | ((u32)f2bf(f0.y) << 16);
    c0.y = (u32)f2bf(f0.z) | ((u32)f2bf(f0.w) << 16);
    c0.z = (u32)f2bf(f1.x) | ((u32)f2bf(f1.y) << 16);
    c0.w = (u32)f2bf(f1.z) | ((u32)f2bf(f1.w) << 16);
    c1.x = (u32)f2bf(f2.x) | ((u32)f2bf(f2.y) << 16);
    c1.y = (u32)f2bf(f2.z) | ((u32)f2bf(f2.w) << 16);
    c1.z = (u32)f2bf(f3.x) | ((u32)f2bf(f3.y) << 16);
    c1.w = (u32)f2bf(f3.z) | ((u32)f2bf(f3.w) << 16);
    *(u32x4*)(smem + awoff0) = c0;
    *(u32x4*)(smem + awoff1) = c1;
#pragma unroll
    for (int i = 0; i < 8; ++i)
      gload_lds16(bsrc_base + i * 1024, smem + 16384 + bdoff + i * 1024);
  }
  __syncthreads();

  for (int it = 0; it < NTILE_IT; ++it) {
    int cur = it & 1;
    char* Acur = smem + (cur ? 8192 : 0);
    char* Bcur = smem + 16384 + (cur ? 32768 : 0);
    char* Anxt = smem + (cur ? 0 : 8192);
    char* Bnxt = smem + 16384 + (cur ? 0 : 32768);
    bool has = (it + 1 < NTILE_IT);
    float4 f0n, f1n, f2n, f3n;
    if (has) {
      // issue next A loads (regs) + next B global->LDS early
      const float4* ap = (const float4*)(ap_base + (it + 1) * 64);
      f0n = ap[0]; f1n = ap[1]; f2n = ap[2]; f3n = ap[3];
      const char* bs = bsrc_base + (size_t)(it + 1) * 32768;
#pragma unroll
      for (int i = 0; i < 8; ++i)
        gload_lds16(bs + i * 1024, Bnxt + bdoff + i * 1024);
    }
    // compute current tile
    bf16x8 af[4][2], bfv[4][2];
#pragma unroll
    for (int ksub = 0; ksub < 2; ++ksub) {
#pragma unroll
      for (int mf = 0; mf < 4; ++mf) af[mf][ksub] = *(const bf16x8*)(Acur + aoff[mf][ksub]);
#pragma unroll
      for (int nf = 0; nf < 4; ++nf) bfv[nf][ksub] = *(const bf16x8*)(Bcur + boff[nf][ksub]);
    }
#pragma unroll
    for (int ksub = 0; ksub < 2; ++ksub)
#pragma unroll
      for (int mf = 0; mf < 4; ++mf)
#pragma unroll
        for (int nf = 0; nf < 4; ++nf)
          acc[mf][nf] = __builtin_amdgcn_mfma_f32_16x16x32_bf16(af[mf][ksub], bfv[nf][ksub], acc[mf][nf], 0, 0, 0);
    if (has) {
      // convert + write next A late (loads have drained under the MFMAs)
      u32x4 c0, c1;
      c0.x = (u32)f2bf(f0n.x) | ((u32)f2bf(f0n.y) << 16);
      c0.y = (u32)f2bf(f0n.z) | ((u32)f2bf(f0n.w) << 16);
      c0.z = (u32)f2bf(f1n.x) | ((u32)f2bf(f1n.y) << 16);
      c0.w = (u32)f2bf(f1n.z) | ((u32)f2bf(f1n.w) << 16);
      c1.x = (u32)f2bf(f2n.x) | ((u32)f2bf(f2n.y) << 16);
      c1.y = (u32)f2bf(f2n.z) | ((u32)f2bf(f2n.w) << 16);
      c1.z = (u32)f2bf(f3n.x) | ((u32)f2bf(f3n.y) << 16);
      c1.w = (u32)f2bf(f3n.z) | ((u32)f2bf(f3n.w) << 16);
      *(u32x4*)(Anxt + awoff0) = c0;
      *(u32x4*)(Anxt + awoff1) = c1;
    }
    __syncthreads();   // drains B gload_lds (vmcnt) + A ds_write for next iter
  }
  float* pb = part + (size_t)ks * 524288;
#pragma unroll
  for (int mf = 0; mf < 4; ++mf) {
    int row = mt * 64 + mf * 16 + kgrp * 4;
#pragma unroll
    for (int nf = 0; nf < 4; ++nf) {
      int col = wv * 64 + nf * 16 + row16;
#pragma unroll
      for (int rr = 0; rr < 4; ++rr)
        pb[(size_t)(row + rr) * 256 + col] = acc[mf][nf][rr];
    }
  }
}

// ---------------- chunked sequential greedy NMS + compact to rois ----------------
__global__ __launch_bounds__(64) void k_nms(const u32* __restrict__ mask,
    const float* __restrict__ tbox, const float* __restrict__ tsc,
    float* __restrict__ rois, float* __restrict__ rsc)
{
  int b = blockIdx.x;
  int lane = threadIdx.x;
  int el = lane & 31;
  const u32* M = mask + (size_t)b * 1024 * 32;
  u32 R = 0;
  u32 cur[32], nxt[32];
#pragma unroll
  for (int i = 0; i < 32; ++i) cur[i] = M[(size_t)(i * 32 + el)];
#pragma unroll 1
  for (int c = 0; c < 32; ++c) {
    if (c < 31) {
      int nb = (c + 1) * 1024 + el;
#pragma unroll
      for (int i = 0; i < 32; ++i) nxt[i] = M[(size_t)(nb + i * 32)];
    }
    u32 w = R;
#pragma unroll
    for (int i = 0; i < 32; ++i) w |= ((w >> i) & 1u) ? 0u : cur[i];
    u32 wfin = __shfl(w, c, 64);
#pragma unroll
    for (int i = 0; i < 32; ++i) R |= ((wfin >> i) & 1u) ? 0u : cur[i];
#pragma unroll
    for (int i = 0; i < 32; ++i) cur[i] = nxt[i];
  }
  u32 keepw = (lane < 32) ? ~R : 0u;
  int c = __popc(keepw);
  int pre = c;
  for (int d = 1; d < 64; d <<= 1) {
    int v = __shfl_up(pre, d, 64);
    if (lane >= d) pre += v;
  }
  int total = __shfl(pre, 31, 64);
  int base = pre - c;
  if (lane < 32) {
    u32 w = keepw;
    int rank = base;
    while (w) {
      int bit = __ffs(w) - 1;
      w &= w - 1;
      if (rank < 512) {
        int r = lane * 32 + bit;
        const float* tb = tbox + ((size_t)b * 1024 + r) * 7;
        float* rp = rois + ((size_t)b * 512 + rank) * 7;
        rp[0] = tb[0]; rp[1] = tb[1]; rp[2] = tb[2]; rp[3] = tb[3];
        rp[4] = tb[4]; rp[5] = tb[5]; rp[6] = tb[6];
        rsc[b * 512 + rank] = tsc[b * 1024 + r];
      }
      rank++;
    }
  }
  for (int z = total + lane; z < 512; z += 64) {
    float* rp = rois + ((size_t)b * 512 + z) * 7;
    rp[0] = rp[1] = rp[2] = rp[3] = rp[4] = rp[5] = rp[6] = 0.0f;
    rsc[b * 512 + z] = 0.0f;
  }
}

// ---------------- one 256x256 layer (4 rows per thread-half) + BN + ReLU ----------------
__device__ __forceinline__ void layer4(const float (*IN)[256], const float* __restrict__ W,
    const float* __restrict__ g, const float* __restrict__ bb, float (*OUT)[256], int t, int h)
{
  float acc[4] = {0, 0, 0, 0};
  const float* Wrow = W + (size_t)t * 256;
  for (int k = 0; k < 256; k += 4) {
    float4 w4 = *(const float4*)&Wrow[k];
#pragma unroll
    for (int r = 0; r < 4; ++r) {
      float4 xv = *(const float4*)&IN[h * 4 + r][k];
      acc[r] = fmaf(xv.x, w4.x, acc[r]);
      acc[r] = fmaf(xv.y, w4.y, acc[r]);
      acc[r] = fmaf(xv.z, w4.z, acc[r]);
      acc[r] = fmaf(xv.w, w4.w, acc[r]);
    }
  }
  float sc = g[t] / sqrtf(1.0f + 1e-5f);
  float bv = bb[t];
#pragma unroll
  for (int r = 0; r < 4; ++r)
    OUT[h * 4 + r][t] = fmaxf(fmaf(acc[r], sc, bv), 0.0f);
}

// ---------------- fused head chain (512 threads) ----------------
__global__ __launch_bounds__(512) void k_chain(const float* __restrict__ part,
    const float* __restrict__ Ws2, const float* __restrict__ Wc1, const float* __restrict__ Wc2,
    const float* __restrict__ Wr1, const float* __restrict__ Wr2,
    const float* __restrict__ g1, const float* __restrict__ b1,
    const float* __restrict__ g2, const float* __restrict__ b2,
    const float* __restrict__ gc1, const float* __restrict__ bc1,
    const float* __restrict__ gc2, const float* __restrict__ bc2,
    const float* __restrict__ gr1, const float* __restrict__ br1,
    const float* __restrict__ gr2, const float* __restrict__ br2,
    const float* __restrict__ Wc3, const float* __restrict__ bc3,
    const float* __restrict__ Wr3, const float* __restrict__ br3,
    const float* __restrict__ rois, const float* __restrict__ rsc,
    float* __restrict__ out)
{
  int bid = blockIdx.x, tid = threadIdx.x;
  int t = tid & 255, h = tid >> 8;        // h: row-half (rows h*4..h*4+3)
  __shared__ __align__(16) float bufX[8][256];
  __shared__ __align__(16) float bufY[8][256];
  __shared__ __align__(16) float bufC[8][256];
  __shared__ __align__(16) float bufR[8][256];
  __shared__ float hd[64];
  {
    float sc = g1[t] / sqrtf(1.0f + 1e-5f);
    float bv = b1[t];
#pragma unroll
    for (int r = 0; r < 4; ++r) {
      int row = h * 4 + r;
      float s = 0.f;
#pragma unroll
      for (int ks = 0; ks < KSPLIT; ++ks)
        s += part[(size_t)ks * 524288 + (size_t)(bid * 8 + row) * 256 + t];
      bufX[row][t] = fmaxf(fmaf(s, sc, bv), 0.0f);
    }
  }
  __syncthreads();
  layer4(bufX, Ws2, g2, b2, bufY, t, h);          // x2
  __syncthreads();
  layer4(bufY, Wc1, gc1, bc1, bufC, t, h);        // c1
  layer4(bufY, Wr1, gr1, br1, bufR, t, h);        // r1
  __syncthreads();
  layer4(bufC, Wc2, gc2, bc2, bufX, t, h);        // c2 -> bufX
  layer4(bufR, Wr2, gr2, br2, bufY, t, h);        // r2 -> bufY
  __syncthreads();
  int wv = tid >> 6, ln = tid & 63;
  for (int task = wv; task < 64; task += 8) {
    float p;
    if (task < 8) {
      float4 yv = *(const float4*)&bufX[task][ln * 4];
      float4 w4 = ((const float4*)Wc3)[ln];
      p = yv.x * w4.x + yv.y * w4.y + yv.z * w4.z + yv.w * w4.w;
    } else {
      int i = task - 8, row = i / 7, j = i % 7;
      float4 yv = *(const float4*)&bufY[row][ln * 4];
      float4 w4 = ((const float4*)(Wr3 + j * 256))[ln];
      p = yv.x * w4.x + yv.y * w4.y + yv.z * w4.z + yv.w * w4.w;
    }
#pragma unroll
    for (int off = 32; off > 0; off >>= 1) p += __shfl_xor(p, off, 64);
    if (ln == 0) hd[task] = p;
  }
  __syncthreads();
  if (tid < 8) {
    int m = bid * 8 + tid;
    float clsv = hd[tid] + bc3[0];
    float rg[7];
#pragma unroll
    for (int j = 0; j < 7; ++j) rg[j] = hd[8 + tid * 7 + j] + br3[j];
    const float* R = rois + (size_t)m * 7;
    float rx = R[0], ry = R[1], rz = R[2], dxa = R[3], dya = R[4], dza = R[5], ra = R[6];
    float diag = sqrtf(dxa * dxa + dya * dya);
    float x = rg[0] * diag, y = rg[1] * diag, z = rg[2] * dza;
    float ex = expf(rg[3]) * dxa, ey = expf(rg[4]) * dya, ez = expf(rg[5]) * dza;
    float hr = rg[6] + ra;
    float cc = cosf(ra), sn = sinf(ra);
    float xr = x * cc - y * sn, yr = x * sn + y * cc;
    float* O = out + (size_t)m * 9;
    O[0] = clsv; O[1] = xr + rx; O[2] = yr + ry; O[3] = z + rz;
    O[4] = ex; O[5] = ey; O[6] = ez; O[7] = hr; O[8] = rsc[m];
  }
}

// ---------------- launch ----------------
extern "C" void kernel_launch(void* const* d_in, const int* in_sizes, int n_in,
                              void* d_out, int out_size, void* d_ws, size_t ws_size,
                              hipStream_t stream)
{
  const float* rpn_box = (const float*)d_in[0];
  const float* rpn_cls = (const float*)d_in[1];
  const float* pooled  = (const float*)d_in[2];
  const float* Ws1 = (const float*)d_in[3];
  const float* g1  = (const float*)d_in[4];
  const float* b1  = (const float*)d_in[5];
  const float* Ws2 = (const float*)d_in[6];
  const float* g2  = (const float*)d_in[7];
  const float* b2  = (const float*)d_in[8];
  const float* Wc1 = (const float*)d_in[9];
  const float* gc1 = (const float*)d_in[10];
  const float* bc1 = (const float*)d_in[11];
  const float* Wc2 = (const float*)d_in[12];
  const float* gc2 = (const float*)d_in[13];
  const float* bc2 = (const float*)d_in[14];
  const float* Wc3 = (const float*)d_in[15];
  const float* bc3 = (const float*)d_in[16];
  const float* Wr1 = (const float*)d_in[17];
  const float* gr1 = (const float*)d_in[18];
  const float* br1 = (const float*)d_in[19];
  const float* Wr2 = (const float*)d_in[20];
  const float* gr2 = (const float*)d_in[21];
  const float* br2 = (const float*)d_in[22];
  const float* Wr3 = (const float*)d_in[23];
  const float* br3 = (const float*)d_in[24];

  if (ws_size < WS_NEED) return;

  char* ws = (char*)d_ws;
  u32* keys = (u32*)(ws + OF_KEYS);
  float* tbox = (float*)(ws + OF_TBOX);
  float* tsc  = (float*)(ws + OF_TSC);
  float* bx1 = (float*)(ws + OF_BX1);
  float* bx2 = (float*)(ws + OF_BX2);
  float* by1 = (float*)(ws + OF_BY1);
  float* by2 = (float*)(ws + OF_BY2);
  float* bar = (float*)(ws + OF_BAR);
  u32* mask = (u32*)(ws + OF_MASK);
  float* roisb = (float*)(ws + OF_ROIS);
  float* rscb  = (float*)(ws + OF_RSC);
  u32* Bsw = (u32*)(ws + OF_BSW);
  float* part = (float*)(ws + OF_PART);

  k_fatA<<<1139, 1024, 0, stream>>>(rpn_cls, Ws1, keys, Bsw);
  k_prop<<<4, 1024, 0, stream>>>(keys, rpn_box, tbox, tsc, bx1, bx2, by1, by2, bar);
  k_fatB<<<768, 256, 0, stream>>>(pooled, Bsw, part, bx1, bx2, by1, by2, bar, mask);
  k_nms<<<4, 64, 0, stream>>>(mask, tbox, tsc, roisb, rscb);
  k_chain<<<256, 512, 0, stream>>>(part, Ws2, Wc1, Wc2, Wr1, Wr2,
                                   g1, b1, g2, b2, gc1, bc1, gc2, bc2,
                                   gr1, br1, gr2, br2, Wc3, bc3, Wr3, br3,
                                   roisb, rscb, (float*)d_out);
}